// Round 2
// baseline (13718.910 us; speedup 1.0000x reference)
//
#include <hip/hip_runtime.h>
#include <stdint.h>

// ---------------------------------------------------------------------------
// ComplexApproximateBNN, round 5b (compile fix of R5). One persistent
// cooperative kernel replaces the 512 step dispatches (R4: 17.3 us/dispatch
// vs ~3 us of real work).
//  - step_loop: 256 blocks x 512 threads (1 block/CU), runs all 128 steps;
//    hand-rolled device-scope grid barrier between the 4 layer phases
//    (syncthreads -> release fence -> atomic arrive -> spin -> acquire fence
//    -> syncthreads). Launched with hipLaunchCooperativeKernel.
//  - per-phase GEMM body identical to R4's step_gemm8 (K split 8 ways,
//    full unroll, LDS reduce, fused l2norm via ss atomics).
//  - h0 precompute, batched y GEMM, bf16 converts unchanged.
// 8 dispatches total.
// ---------------------------------------------------------------------------

typedef __bf16 bf16;
typedef __attribute__((ext_vector_type(8))) __bf16 bf16x8;
typedef __attribute__((ext_vector_type(4))) float f32x4;

#define BATCH 64
#define TSTEPS 128
#define INDIM 512
#define XDIM 2048
#define OUTDIM 256
#define SLOTE ((size_t)BATCH * XDIM)  // elements per [b][2048] slot
#define NBLOCKS 256

__device__ __forceinline__ float apply_act(float h, int id) {
  switch (id) {
    case 0: return fmaxf(h, 0.0f);                       // relu
    case 1: return 1.0f / (1.0f + __expf(-h));           // sigmoid
    case 2: return tanhf(h);                             // tanh
    case 3: return h >= 0.0f ? h : 0.1f * h;             // leaky 0.1
    default: {                                           // selu
      const float sc = 1.0507009873554805f;
      const float al = 1.6732632423543772f;
      return h > 0.0f ? sc * h : sc * al * (__expf(h) - 1.0f);
    }
  }
}

// Grid-wide barrier. Entry __syncthreads drains each thread's global stores
// (compiler emits s_waitcnt vmcnt(0) before s_barrier), so they are in the
// XCD L2; thread 0's agent-release fence makes them device visible before
// the arrival tick; acquire fence after the spin invalidates L1/L2 so
// post-barrier reads see fresh data.
__device__ __forceinline__ void grid_sync(unsigned* bar, unsigned target) {
  __syncthreads();
  if (threadIdx.x == 0) {
    __builtin_amdgcn_fence(__ATOMIC_RELEASE, "agent");
    __hip_atomic_fetch_add(bar, 1u, __ATOMIC_RELAXED, __HIP_MEMORY_SCOPE_AGENT);
    while (__hip_atomic_load(bar, __ATOMIC_RELAXED, __HIP_MEMORY_SCOPE_AGENT) < target) {
      __builtin_amdgcn_s_sleep(1);
    }
    __builtin_amdgcn_fence(__ATOMIC_ACQUIRE, "agent");
  }
  __syncthreads();
}

// One layer: C[64,2048] = act(concat(A1,A2)[64,4096] @ W[2048,4096]^T + b).
// Body identical to R4's step_gemm8. Block bid: n-tile = bid&127 (16 cols),
// m-half = bid>>7 (32 rows). 8 waves: w<4 -> A1, w>=4 -> A2, k=512 each.
template <bool SCALE_A2, bool EMIT_SS>
__device__ __forceinline__ void layer_gemm(
    const int tid, const int nblk, const int mrow,
    const bf16* __restrict__ A1, const bf16* __restrict__ A2,
    const bf16* __restrict__ W, const float* __restrict__ bias,
    const int* __restrict__ acts, const float* __restrict__ ss_in,
    float* __restrict__ ss_out, bf16* __restrict__ outb,
    float (&red)[8][32][17]) {
  const int lane = tid & 63;
  const int w = tid >> 6;        // 0..7
  const int l15 = lane & 15;
  const int kb8 = (lane >> 4) * 8;

  const bf16* As = (w >= 4) ? A2 : A1;
  const int koff = (w & 3) * 512;   // offset within source
  const int wk = w * 512;           // global k for W

  const bf16* ap0 = As + (size_t)(mrow + l15) * 2048 + koff + kb8;
  const bf16* ap1 = ap0 + 16 * 2048;
  const bf16* bpw = W + (size_t)(nblk + l15) * 4096 + wk + kb8;

  f32x4 acc0 = {0.f, 0.f, 0.f, 0.f};
  f32x4 acc1 = {0.f, 0.f, 0.f, 0.f};
#pragma unroll
  for (int k = 0; k < 512; k += 32) {
    bf16x8 a0 = *(const bf16x8*)(ap0 + k);
    bf16x8 a1 = *(const bf16x8*)(ap1 + k);
    bf16x8 b  = *(const bf16x8*)(bpw + k);
    acc0 = __builtin_amdgcn_mfma_f32_16x16x32_bf16(a0, b, acc0, 0, 0, 0);
    acc1 = __builtin_amdgcn_mfma_f32_16x16x32_bf16(a1, b, acc1, 0, 0, 0);
  }

  const int q4 = lane >> 4;
#pragma unroll
  for (int r = 0; r < 4; r++) red[w][q4 * 4 + r][l15] = acc0[r];
#pragma unroll
  for (int r = 0; r < 4; r++) red[w][16 + q4 * 4 + r][l15] = acc1[r];
  __syncthreads();

  if (tid < 256) {
    const int row = tid >> 3;      // 0..31
    const int c0 = (tid & 7) * 2;  // even col
    const int rg = mrow + row;

    float scale = 1.0f;
    if (SCALE_A2) scale = 1.0f / fmaxf(sqrtf(ss_in[rg]), 1e-12f);

    float v[2];
#pragma unroll
    for (int j = 0; j < 2; j++) {
      int c = c0 + j;
      float lo = red[0][row][c] + red[1][row][c] + red[2][row][c] + red[3][row][c];
      float hi = red[4][row][c] + red[5][row][c] + red[6][row][c] + red[7][row][c];
      float pre = (SCALE_A2 ? (lo + scale * hi) : (lo + hi)) + bias[nblk + c];
      v[j] = apply_act(pre, acts[nblk + c]);
    }
    if (EMIT_SS) {
      float ss = v[0] * v[0] + v[1] * v[1];
      ss += __shfl_xor(ss, 1);
      ss += __shfl_xor(ss, 2);
      ss += __shfl_xor(ss, 4);
      if ((tid & 7) == 0) atomicAdd(ss_out + rg, ss);
    }
    union { bf16 b2[2]; uint32_t u; } pk;
    pk.b2[0] = (bf16)v[0];
    pk.b2[1] = (bf16)v[1];
    *(uint32_t*)(outb + (size_t)rg * XDIM + nblk + c0) = pk.u;
  }
}

struct StepParams {
  bf16* h0;           // [128][64][2048], slices also reused as h4 slots 2..
  bf16* extra;        // h4 slots 0,1
  bf16* h1;
  bf16* h2a;
  bf16* h2b;
  bf16* h3;
  const bf16* whb;    // [4][2048][4096]
  const float* b_h;   // [4][2048]
  const int* acts;    // [5][2048]
  float* ss_li;       // [(T+1)*64]
  float* ss_bp;       // [(T+1)*64]
  unsigned* bar;      // grid barrier counter (zeroed)
};

__global__ __launch_bounds__(512, 2) void step_loop(StepParams p) {
  __shared__ float red[8][32][17];
  const int tid = threadIdx.x;
  const int bid = blockIdx.x;
  const int nblk = (bid & 127) * 16;   // 16 output cols
  const int mrow = (bid >> 7) * 32;    // 32 batch rows; bid and bid+128 share
                                       // an XCD (128%8==0) so dup W hits L2
  const size_t wstr = (size_t)XDIM * 2 * XDIM;
  unsigned tgt = 0;

  for (int t = 0; t < TSTEPS; t++) {
    const bf16* h4t = (t < 2) ? p.extra + (size_t)t * SLOTE
                              : p.h0 + (size_t)(t - 2) * SLOTE;
    bf16* h4n = (t + 1 < 2) ? p.extra + (size_t)(t + 1) * SLOTE
                            : p.h0 + (size_t)(t - 1) * SLOTE;
    bf16* h2n = (t & 1) ? p.h2b : p.h2a;
    const bf16* h2o = (t & 1) ? p.h2a : p.h2b;

    // h1 = act([h0_t, norm(h4_t)] @ W0^T + b0)
    layer_gemm<true, false>(tid, nblk, mrow, p.h0 + (size_t)t * SLOTE, h4t,
                            p.whb, p.b_h, p.acts + XDIM, p.ss_bp + t * BATCH,
                            nullptr, p.h1, red);
    tgt += NBLOCKS; grid_sync(p.bar, tgt);

    // h2 = act([h1, norm(h2_old)] @ W1^T + b1); emit ss_li[t+1]
    layer_gemm<true, true>(tid, nblk, mrow, p.h1, h2o, p.whb + wstr,
                           p.b_h + XDIM, p.acts + 2 * XDIM,
                           p.ss_li + t * BATCH, p.ss_li + (t + 1) * BATCH,
                           h2n, red);
    tgt += NBLOCKS; grid_sync(p.bar, tgt);

    // h3 = act([h2, h1] @ W2^T + b2)
    layer_gemm<false, false>(tid, nblk, mrow, h2n, p.h1, p.whb + 2 * wstr,
                             p.b_h + 2 * XDIM, p.acts + 3 * XDIM, nullptr,
                             nullptr, p.h3, red);
    tgt += NBLOCKS; grid_sync(p.bar, tgt);

    // h4 = act([h3, h2] @ W3^T + b3) -> slot t+1; emit ss_bp[t+1]
    layer_gemm<false, true>(tid, nblk, mrow, p.h3, h2n, p.whb + 3 * wstr,
                            p.b_h + 3 * XDIM, p.acts + 4 * XDIM, nullptr,
                            p.ss_bp + (t + 1) * BATCH, h4n, red);
    tgt += NBLOCKS; grid_sync(p.bar, tgt);
  }
}

// h0 precompute: [8192,512]@[512->2048], rows r=b*128+t remapped to [t][b][n]
__global__ __launch_bounds__(256) void h0_gemm(
    const bf16* __restrict__ A, const bf16* __restrict__ W,
    const float* __restrict__ bias, const int* __restrict__ acts,
    bf16* __restrict__ outp) {
  const int tid = threadIdx.x;
  const int lane = tid & 63;
  const int wv = tid >> 6;
  const int wm = (wv & 1) * 32;
  const int wn = (wv >> 1) * 64;
  const int nblk = blockIdx.x * 128;
  const int mblk = blockIdx.y * 64;
  const int l15 = lane & 15;
  const int kb8 = (lane >> 4) * 8;

  f32x4 acc[2][4];
  const f32x4 zero = {0.f, 0.f, 0.f, 0.f};
#pragma unroll
  for (int i = 0; i < 2; i++)
#pragma unroll
    for (int j = 0; j < 4; j++) acc[i][j] = zero;

  for (int kt = 0; kt < INDIM; kt += 32) {
    bf16x8 a[2], b[4];
#pragma unroll
    for (int mt = 0; mt < 2; mt++) {
      int m = mblk + wm + mt * 16 + l15;
      a[mt] = *(const bf16x8*)(A + (size_t)m * INDIM + kt + kb8);
    }
#pragma unroll
    for (int nt = 0; nt < 4; nt++) {
      int n = nblk + wn + nt * 16 + l15;
      b[nt] = *(const bf16x8*)(W + (size_t)n * INDIM + kt + kb8);
    }
#pragma unroll
    for (int mt = 0; mt < 2; mt++)
#pragma unroll
      for (int nt = 0; nt < 4; nt++)
        acc[mt][nt] = __builtin_amdgcn_mfma_f32_16x16x32_bf16(a[mt], b[nt], acc[mt][nt], 0, 0, 0);
  }

#pragma unroll
  for (int mt = 0; mt < 2; mt++) {
#pragma unroll
    for (int nt = 0; nt < 4; nt++) {
      int n = nblk + wn + nt * 16 + l15;
      float bv = bias[n];
      int aid = acts[n];
#pragma unroll
      for (int rr = 0; rr < 4; rr++) {
        int m = wm + mt * 16 + (lane >> 4) * 4 + rr;
        float v = apply_act(acc[mt][nt][rr] + bv, aid);
        int rowg = mblk + m;  // = b*128 + t
        int bb = rowg >> 7;
        int tt = rowg & 127;
        outp[((size_t)tt * BATCH + bb) * XDIM + n] = (bf16)v;
      }
    }
  }
}

// batched output layer: for each t, y_t = act(h4slot(t+1) @ Wout^T + bout).
// grid (2 n-tiles of 128, 128 t-slots). slot s<2 -> extra, else h0[s-2].
__global__ __launch_bounds__(256) void ybat_gemm(
    const bf16* __restrict__ extra, const bf16* __restrict__ h0,
    const bf16* __restrict__ Wout, const float* __restrict__ bout,
    const int* __restrict__ oact, float* __restrict__ out) {
  const int t = blockIdx.y;
  const int s = t + 1;
  const bf16* A = (s < 2) ? (extra + (size_t)s * SLOTE)
                          : (h0 + (size_t)(s - 2) * SLOTE);
  const int tid = threadIdx.x;
  const int lane = tid & 63;
  const int wv = tid >> 6;
  const int wm = (wv & 1) * 32;
  const int wn = (wv >> 1) * 64;
  const int nblk = blockIdx.x * 128;
  const int l15 = lane & 15;
  const int kb8 = (lane >> 4) * 8;

  f32x4 acc[2][4];
  const f32x4 zero = {0.f, 0.f, 0.f, 0.f};
#pragma unroll
  for (int i = 0; i < 2; i++)
#pragma unroll
    for (int j = 0; j < 4; j++) acc[i][j] = zero;

  for (int kt = 0; kt < XDIM; kt += 32) {
    bf16x8 a[2], b[4];
#pragma unroll
    for (int mt = 0; mt < 2; mt++) {
      int m = wm + mt * 16 + l15;
      a[mt] = *(const bf16x8*)(A + (size_t)m * XDIM + kt + kb8);
    }
#pragma unroll
    for (int nt = 0; nt < 4; nt++) {
      int n = nblk + wn + nt * 16 + l15;
      b[nt] = *(const bf16x8*)(Wout + (size_t)n * XDIM + kt + kb8);
    }
#pragma unroll
    for (int mt = 0; mt < 2; mt++)
#pragma unroll
      for (int nt = 0; nt < 4; nt++)
        acc[mt][nt] = __builtin_amdgcn_mfma_f32_16x16x32_bf16(a[mt], b[nt], acc[mt][nt], 0, 0, 0);
  }

#pragma unroll
  for (int mt = 0; mt < 2; mt++) {
#pragma unroll
    for (int nt = 0; nt < 4; nt++) {
      int n = nblk + wn + nt * 16 + l15;
      float bv = bout[n];
      int aid = oact[n];
#pragma unroll
      for (int rr = 0; rr < 4; rr++) {
        int b = wm + mt * 16 + (lane >> 4) * 4 + rr;  // batch row
        float v = apply_act(acc[mt][nt][rr] + bv, aid);
        out[((size_t)b * TSTEPS + t) * OUTDIM + n] = v;
      }
    }
  }
}

__global__ __launch_bounds__(256) void cvt_bf16(
    const float* __restrict__ in, bf16* __restrict__ out, int n4) {
  int i = blockIdx.x * 256 + threadIdx.x;
  if (i < n4) {
    float4 v = ((const float4*)in)[i];
    union { bf16 b[4]; unsigned long long u; } pk;
    pk.b[0] = (bf16)v.x;
    pk.b[1] = (bf16)v.y;
    pk.b[2] = (bf16)v.z;
    pk.b[3] = (bf16)v.w;
    ((unsigned long long*)out)[i] = pk.u;
  }
}

__global__ __launch_bounds__(256) void zero32(uint32_t* __restrict__ p, int n) {
  int i = blockIdx.x * 256 + threadIdx.x;
  if (i < n) p[i] = 0u;
}

extern "C" void kernel_launch(void* const* d_in, const int* in_sizes, int n_in,
                              void* d_out, int out_size, void* d_ws, size_t ws_size,
                              hipStream_t stream) {
  const float* x     = (const float*)d_in[0];   // [64,128,512]
  const float* W_in  = (const float*)d_in[1];   // [2048,512]
  const float* b_in  = (const float*)d_in[2];   // [2048]
  const float* W_h   = (const float*)d_in[3];   // [4,2048,4096]
  const float* b_h   = (const float*)d_in[4];   // [4,2048]
  const float* W_out = (const float*)d_in[5];   // [256,2048]
  const float* b_out = (const float*)d_in[6];   // [256]
  const int* act_ids = (const int*)d_in[7];     // [5,2048]
  const int* out_act = (const int*)d_in[8];     // [256]
  float* out = (float*)d_out;                   // [64,128,256]

  char* w = (char*)d_ws;
  bf16* xbf   = (bf16*)w; w += (size_t)BATCH * TSTEPS * INDIM * 2;   // 8 MB
  bf16* winb  = (bf16*)w; w += (size_t)XDIM * INDIM * 2;             // 2 MB
  bf16* whb   = (bf16*)w; w += (size_t)4 * XDIM * (2 * XDIM) * 2;    // 64 MB
  bf16* woutb = (bf16*)w; w += (size_t)OUTDIM * XDIM * 2;            // 1 MB
  bf16* h0    = (bf16*)w; w += (size_t)TSTEPS * SLOTE * 2;           // 32 MB (doubles as h4 slots 2..)
  bf16* h1    = (bf16*)w; w += SLOTE * 2;
  bf16* h3    = (bf16*)w; w += SLOTE * 2;
  // ---- zero region ----
  char* zstart = w;
  bf16* extra = (bf16*)w; w += 2 * SLOTE * 2;   // h4 slots 0,1 (slot 0 must be 0)
  bf16* h2a   = (bf16*)w; w += SLOTE * 2;
  bf16* h2b   = (bf16*)w; w += SLOTE * 2;
  float* ss_li = (float*)w; w += (size_t)(TSTEPS + 1) * BATCH * 4;
  float* ss_bp = (float*)w; w += (size_t)(TSTEPS + 1) * BATCH * 4;
  unsigned* bar = (unsigned*)w; w += 256;       // barrier counter (padded)
  int zero_u32 = (int)((w - zstart) / 4);

  cvt_bf16<<<4096, 256, 0, stream>>>(x, xbf, (BATCH * TSTEPS * INDIM) / 4);
  cvt_bf16<<<1024, 256, 0, stream>>>(W_in, winb, (XDIM * INDIM) / 4);
  cvt_bf16<<<32768, 256, 0, stream>>>(W_h, whb, (4 * XDIM * 2 * XDIM) / 4);
  cvt_bf16<<<512, 256, 0, stream>>>(W_out, woutb, (OUTDIM * XDIM) / 4);
  zero32<<<(zero_u32 + 255) / 256, 256, 0, stream>>>((uint32_t*)zstart, zero_u32);
  h0_gemm<<<dim3(16, 128), 256, 0, stream>>>(xbf, winb, b_in, act_ids, h0);

  StepParams sp;
  sp.h0 = h0;
  sp.extra = extra;
  sp.h1 = h1;
  sp.h2a = h2a;
  sp.h2b = h2b;
  sp.h3 = h3;
  sp.whb = whb;
  sp.b_h = b_h;
  sp.acts = act_ids;
  sp.ss_li = ss_li;
  sp.ss_bp = ss_bp;
  sp.bar = bar;
  void* kp[] = {&sp};
  (void)hipLaunchCooperativeKernel((const void*)step_loop, dim3(NBLOCKS),
                                   dim3(512), kp, 0, stream);

  // all y_t in one GEMM over the stored h4 slots
  ybat_gemm<<<dim3(2, TSTEPS), 256, 0, stream>>>(
      extra, h0, woutb, b_out, out_act, out);
}